// Round 9
// baseline (3671.523 us; speedup 1.0000x reference)
//
#include <hip/hip_runtime.h>
#include <hip/hip_bf16.h>
#include <hip/hip_fp16.h>
#include <math.h>

#define UNITS 64
#define DEPTH_EMB 12
#define DEPTH_PAR 5
#define GN_EPS 1e-5f

// ---------------- CSR build ----------------

__global__ void k_deg(const int* __restrict__ dst, int* __restrict__ cnt, int E) {
    int e = blockIdx.x * blockDim.x + threadIdx.x;
    if (e < E) atomicAdd(&cnt[dst[e]], 1);
}

__global__ void k_dinv(const int* __restrict__ cnt, float* __restrict__ dinv, int n) {
    int i = blockIdx.x * blockDim.x + threadIdx.x;
    if (i < n) dinv[i] = rsqrtf(1.0f + (float)cnt[i]);
}

__global__ void k_chunksum(const int* __restrict__ cnt, int* __restrict__ csum, int n) {
    __shared__ int sd[256];
    int base = blockIdx.x * 1024;
    int s = 0;
    for (int i = threadIdx.x; i < 1024; i += 256) {
        int idx = base + i;
        if (idx < n) s += cnt[idx];
    }
    sd[threadIdx.x] = s;
    __syncthreads();
    for (int off = 128; off > 0; off >>= 1) {
        if (threadIdx.x < off) sd[threadIdx.x] += sd[threadIdx.x + off];
        __syncthreads();
    }
    if (threadIdx.x == 0) csum[blockIdx.x] = sd[0];
}

__global__ void k_scansum(const int* __restrict__ csum, int* __restrict__ coff,
                          int* __restrict__ rowptr, int nchunks) {
    __shared__ int sd[256];
    int tid = threadIdx.x;
    int v = (tid < nchunks) ? csum[tid] : 0;
    sd[tid] = v;
    __syncthreads();
    for (int off = 1; off < 256; off <<= 1) {
        int t = (tid >= off) ? sd[tid - off] : 0;
        __syncthreads();
        sd[tid] += t;
        __syncthreads();
    }
    if (tid < nchunks) coff[tid] = sd[tid] - v;
    if (tid == 0) rowptr[0] = 0;
}

__global__ void k_scanfinal(const int* __restrict__ cnt, const int* __restrict__ coff,
                            int* __restrict__ rowptr, int n) {
    __shared__ int sd[1024];
    int base = blockIdx.x * 1024;
    int tid = threadIdx.x;
    int idx = base + tid;
    int v = (idx < n) ? cnt[idx] : 0;
    sd[tid] = v;
    __syncthreads();
    for (int off = 1; off < 1024; off <<= 1) {
        int t = (tid >= off) ? sd[tid - off] : 0;
        __syncthreads();
        sd[tid] += t;
        __syncthreads();
    }
    if (idx < n) rowptr[idx + 1] = coff[blockIdx.x] + sd[tid];
}

__global__ void k_fill(const int* __restrict__ src, const int* __restrict__ dst,
                       const int* __restrict__ rowptr, int* __restrict__ fill,
                       int* __restrict__ srcs, int E) {
    int e = blockIdx.x * blockDim.x + threadIdx.x;
    if (e >= E) return;
    int s = src[e], d = dst[e];
    int p = rowptr[d] + atomicAdd(&fill[d], 1);
    srcs[p] = s;
}

// ---------------- layer 0: h2 = f16(dinv * (x @ w0)), row-major [N][64] ----------------

__global__ void k_l0(const float* __restrict__ x, const float* __restrict__ w0,
                     const float* __restrict__ dinv, __half* __restrict__ h2, int n) {
    int gid = blockIdx.x * blockDim.x + threadIdx.x;
    if (gid >= n * UNITS) return;
    int node = gid >> 6, c = gid & 63;
    h2[gid] = __float2half(x[node] * w0[c] * dinv[node]);
}

// ---------------- gather: h[d] = dinv[d]*(sum srcs rows + own row) + b ----------------

template <int DO_STATS>
__global__ void k_gather(const __half* __restrict__ h2, float* __restrict__ h,
                         const int* __restrict__ rowptr, const int* __restrict__ srcs,
                         const float* __restrict__ dinv, const float* __restrict__ b,
                         float* __restrict__ stats, int n) {
    int lane = threadIdx.x & 63;
    int wib = threadIdx.x >> 6;
    int wpb = blockDim.x >> 6;
    int gwave = blockIdx.x * wpb + wib;
    int nwaves = gridDim.x * wpb;
    float bj = b[lane];
    float s1 = 0.0f, s2 = 0.0f;

    for (int nd = gwave; nd < n; nd += nwaves) {
        int node = __builtin_amdgcn_readfirstlane(nd);
        int beg = rowptr[node], end = rowptr[node + 1];
        float di = dinv[node];
        float acc0 = __half2float(h2[(size_t)node * UNITS + lane]);   // self row
        float acc1 = 0.0f, acc2 = 0.0f, acc3 = 0.0f;
        int j = beg;
        for (; j + 8 <= end; j += 8) {
            int i0 = srcs[j + 0], i1 = srcs[j + 1], i2 = srcs[j + 2], i3 = srcs[j + 3];
            int i4 = srcs[j + 4], i5 = srcs[j + 5], i6 = srcs[j + 6], i7 = srcs[j + 7];
            float v0 = __half2float(h2[(size_t)i0 * UNITS + lane]);
            float v1 = __half2float(h2[(size_t)i1 * UNITS + lane]);
            float v2 = __half2float(h2[(size_t)i2 * UNITS + lane]);
            float v3 = __half2float(h2[(size_t)i3 * UNITS + lane]);
            float v4 = __half2float(h2[(size_t)i4 * UNITS + lane]);
            float v5 = __half2float(h2[(size_t)i5 * UNITS + lane]);
            float v6 = __half2float(h2[(size_t)i6 * UNITS + lane]);
            float v7 = __half2float(h2[(size_t)i7 * UNITS + lane]);
            acc0 += v0; acc1 += v1; acc2 += v2; acc3 += v3;
            acc0 += v4; acc1 += v5; acc2 += v6; acc3 += v7;
        }
        for (; j + 4 <= end; j += 4) {
            int i0 = srcs[j + 0], i1 = srcs[j + 1], i2 = srcs[j + 2], i3 = srcs[j + 3];
            float v0 = __half2float(h2[(size_t)i0 * UNITS + lane]);
            float v1 = __half2float(h2[(size_t)i1 * UNITS + lane]);
            float v2 = __half2float(h2[(size_t)i2 * UNITS + lane]);
            float v3 = __half2float(h2[(size_t)i3 * UNITS + lane]);
            acc0 += v0; acc1 += v1; acc2 += v2; acc3 += v3;
        }
        for (; j < end; ++j) acc0 += __half2float(h2[(size_t)srcs[j] * UNITS + lane]);
        float acc = (acc0 + acc1) + (acc2 + acc3);
        float hv = fmaf(acc, di, bj);
        h[(size_t)node * UNITS + lane] = hv;
        if (DO_STATS) {
            s1 += hv;
            s2 = fmaf(hv, hv, s2);
        }
    }

    if (DO_STATS) {
        __shared__ float sd[2][4][UNITS];
        sd[0][wib][lane] = s1;
        sd[1][wib][lane] = s2;
        __syncthreads();
        if (threadIdx.x < UNITS) {
            float a1 = 0.0f, a2 = 0.0f;
            for (int r = 0; r < wpb; ++r) {
                a1 += sd[0][r][lane];
                a2 += sd[1][r][lane];
            }
            atomicAdd(&stats[lane], a1);
            atomicAdd(&stats[UNITS + lane], a2);
        }
    }
}

// ---------------- GraphNorm finalize: sAB[0:64]=A, sAB[64:128]=B ----------------

__global__ void k_stats_final(const float* __restrict__ stats, const float* __restrict__ gamma,
                              const float* __restrict__ beta, const float* __restrict__ alpha,
                              float* __restrict__ sAB, float inv_n) {
    int c = threadIdx.x;
    if (c >= UNITS) return;
    float m = stats[c] * inv_n;
    float ex2 = stats[UNITS + c] * inv_n;
    float a = alpha[c];
    float var = ex2 - m * m * (2.0f * a - a * a);
    float rs = rsqrtf(var + GN_EPS);
    float g = gamma[c] * rs;
    sAB[c] = g;
    sAB[UNITS + c] = beta[c] - g * a * m;
}

// ---------------- fused GN+SiLU+linear (uniform scalar path, NO cross-lane) ----------------
// out_h2 = f16( dinv[node] * ( silu(A*in[node]+B) @ W ) )

__global__ void k_linear_gnl(const float* __restrict__ in, __half* __restrict__ out,
                             const float* __restrict__ W, const float* __restrict__ dinv,
                             const float* __restrict__ sAB, int n) {
    int lane = threadIdx.x & 63;
    int wib = threadIdx.x >> 6;
    int wpb = blockDim.x >> 6;
    int gwave = blockIdx.x * wpb + wib;
    int nwaves = gridDim.x * wpb;

    float w[UNITS];
#pragma unroll
    for (int k = 0; k < UNITS; ++k) w[k] = W[k * UNITS + lane];

    for (int nd = gwave; nd < n; nd += nwaves) {
        int node = __builtin_amdgcn_readfirstlane(nd);
        const float* __restrict__ row = in + (size_t)node * UNITS;
        float di = dinv[node];
        float a0 = 0.0f, a1 = 0.0f, a2 = 0.0f, a3 = 0.0f;
#pragma unroll
        for (int k = 0; k < UNITS; k += 4) {
            float t0 = fmaf(row[k + 0], sAB[k + 0], sAB[UNITS + k + 0]);
            float t1 = fmaf(row[k + 1], sAB[k + 1], sAB[UNITS + k + 1]);
            float t2 = fmaf(row[k + 2], sAB[k + 2], sAB[UNITS + k + 2]);
            float t3 = fmaf(row[k + 3], sAB[k + 3], sAB[UNITS + k + 3]);
            t0 = t0 / (1.0f + __expf(-t0));
            t1 = t1 / (1.0f + __expf(-t1));
            t2 = t2 / (1.0f + __expf(-t2));
            t3 = t3 / (1.0f + __expf(-t3));
            a0 = fmaf(t0, w[k + 0], a0);
            a1 = fmaf(t1, w[k + 1], a1);
            a2 = fmaf(t2, w[k + 2], a2);
            a3 = fmaf(t3, w[k + 3], a3);
        }
        float acc = (a0 + a1) + (a2 + a3);
        out[(size_t)node * UNITS + lane] = __float2half(acc * di);
    }
}

// ---------------- ParNet linear: out = relu(in + in @ W + b) ----------------

__global__ void k_linear_par(const float* __restrict__ in, float* __restrict__ out,
                             const float* __restrict__ W, const float* __restrict__ b, int n) {
    int lane = threadIdx.x & 63;
    int wib = threadIdx.x >> 6;
    int wpb = blockDim.x >> 6;
    int gwave = blockIdx.x * wpb + wib;
    int nwaves = gridDim.x * wpb;

    float w[UNITS];
#pragma unroll
    for (int k = 0; k < UNITS; ++k) w[k] = W[k * UNITS + lane];
    float bj = b[lane];

    for (int nd = gwave; nd < n; nd += nwaves) {
        int node = __builtin_amdgcn_readfirstlane(nd);
        const float* __restrict__ row = in + (size_t)node * UNITS;
        float a0 = 0.0f, a1 = 0.0f, a2 = 0.0f, a3 = 0.0f;
#pragma unroll
        for (int k = 0; k < UNITS; k += 4) {
            a0 = fmaf(row[k + 0], w[k + 0], a0);
            a1 = fmaf(row[k + 1], w[k + 1], a1);
            a2 = fmaf(row[k + 2], w[k + 2], a2);
            a3 = fmaf(row[k + 3], w[k + 3], a3);
        }
        float acc = (a0 + a1) + (a2 + a3) + row[lane] + bj;
        acc = fmaxf(acc, 0.0f);
        out[(size_t)node * UNITS + lane] = acc;
    }
}

// ---------------- ParNet final linear + head fused ----------------

__global__ void k_linear_head(const float* __restrict__ in, const float* __restrict__ W,
                              const float* __restrict__ b, const float* __restrict__ wl,
                              const float* __restrict__ bl, float* __restrict__ out, int n) {
    int lane = threadIdx.x & 63;
    int wib = threadIdx.x >> 6;
    int wpb = blockDim.x >> 6;
    int gwave = blockIdx.x * wpb + wib;
    int nwaves = gridDim.x * wpb;

    float w[UNITS];
#pragma unroll
    for (int k = 0; k < UNITS; ++k) w[k] = W[k * UNITS + lane];
    float bj = b[lane];
    float wv = wl[lane];
    float blv = bl[0];

    for (int nd = gwave; nd < n; nd += nwaves) {
        int node = __builtin_amdgcn_readfirstlane(nd);
        const float* __restrict__ row = in + (size_t)node * UNITS;
        float a0 = 0.0f, a1 = 0.0f, a2 = 0.0f, a3 = 0.0f;
#pragma unroll
        for (int k = 0; k < UNITS; k += 4) {
            a0 = fmaf(row[k + 0], w[k + 0], a0);
            a1 = fmaf(row[k + 1], w[k + 1], a1);
            a2 = fmaf(row[k + 2], w[k + 2], a2);
            a3 = fmaf(row[k + 3], w[k + 3], a3);
        }
        float acc = (a0 + a1) + (a2 + a3) + row[lane] + bj;
        acc = fmaxf(acc, 0.0f);
        float p = acc * wv;
#pragma unroll
        for (int off = 32; off > 0; off >>= 1) p += __shfl_xor(p, off, 64);
        if (lane == 0) out[node] = 1.0f / (1.0f + __expf(-(p + blv)));
    }
}

// ---------------- host launch ----------------

extern "C" void kernel_launch(void* const* d_in, const int* in_sizes, int n_in,
                              void* d_out, int out_size, void* d_ws, size_t ws_size,
                              hipStream_t stream) {
    const float* x = (const float*)d_in[0];
    const int* ei = (const int*)d_in[1];
    const float* conv_w0 = (const float*)d_in[2];
    const float* conv_w = (const float*)d_in[3];
    const float* conv_b = (const float*)d_in[4];
    const float* gn_gamma = (const float*)d_in[5];
    const float* gn_beta = (const float*)d_in[6];
    const float* gn_alpha = (const float*)d_in[7];
    const float* phe_w = (const float*)d_in[8];
    const float* phe_b = (const float*)d_in[9];
    const float* phe_wl = (const float*)d_in[10];
    const float* phe_bl = (const float*)d_in[11];
    const float* heu_w = (const float*)d_in[12];
    const float* heu_b = (const float*)d_in[13];
    const float* heu_wl = (const float*)d_in[14];
    const float* heu_bl = (const float*)d_in[15];

    const int N = in_sizes[0];
    const int E = in_sizes[1] / 2;
    const int NC = N * UNITS;
    const int NCHUNK1024 = (N + 1023) / 1024;

    const int* src = ei;
    const int* dstp = ei + E;

    char* w = (char*)d_ws;
    float* dinv = (float*)w;  w += (size_t)N * 4;
    float* h = (float*)w;     w += (size_t)NC * 4;
    float* hx = (float*)w;    w += (size_t)NC * 4;   // f16 h2 (embedding) / parnet scratch
    float* h3 = (float*)w;    w += (size_t)NC * 4;   // parnet scratch
    float* stats = (float*)w; w += (size_t)DEPTH_EMB * 128 * 4;
    float* sAB = (float*)w;   w += 128 * 4;
    int* cnt = (int*)w;       w += (size_t)N * 4;
    int* rowptr = (int*)w;    w += (size_t)(N + 1) * 4;
    int* fillc = (int*)w;     w += (size_t)N * 4;
    int* srcs = (int*)w;      w += (size_t)(E + 16) * 4;
    int* csum = (int*)w;      w += 256 * 4;
    int* coff = (int*)w;      w += 256 * 4;

    __half* h2 = (__half*)hx;
    float* out = (float*)d_out;

    const int B = 256;
    const int gE = (E + B - 1) / B;
    const int gN = (N + B - 1) / B;
    const int gNC = (NC + B - 1) / B;

    // ---- CSR build ----
    hipMemsetAsync(cnt, 0, (size_t)N * 4, stream);
    hipMemsetAsync(fillc, 0, (size_t)N * 4, stream);
    hipMemsetAsync(stats, 0, (size_t)DEPTH_EMB * 128 * 4, stream);
    k_deg<<<gE, B, 0, stream>>>(dstp, cnt, E);
    k_dinv<<<gN, B, 0, stream>>>(cnt, dinv, N);
    k_chunksum<<<NCHUNK1024, 256, 0, stream>>>(cnt, csum, N);
    k_scansum<<<1, 256, 0, stream>>>(csum, coff, rowptr, NCHUNK1024);
    k_scanfinal<<<NCHUNK1024, 1024, 0, stream>>>(cnt, coff, rowptr, N);
    k_fill<<<gE, B, 0, stream>>>(src, dstp, rowptr, fillc, srcs, E);

    // ---- GCN embedding ----
    k_l0<<<gNC, B, 0, stream>>>(x, conv_w0, dinv, h2, N);
    for (int i = 0; i < DEPTH_EMB; ++i) {
        float* st = stats + (size_t)i * 128;
        if (i < DEPTH_EMB - 1) {
            k_gather<1><<<2048, B, 0, stream>>>(h2, h, rowptr, srcs, dinv,
                                                conv_b + (size_t)i * UNITS, st, N);
            k_stats_final<<<1, 64, 0, stream>>>(st, gn_gamma + (size_t)i * UNITS,
                                                gn_beta + (size_t)i * UNITS,
                                                gn_alpha + (size_t)i * UNITS,
                                                sAB, 1.0f / (float)N);
            k_linear_gnl<<<2048, B, 0, stream>>>(h, h2, conv_w + (size_t)i * UNITS * UNITS,
                                                 dinv, sAB, N);
        } else {
            k_gather<0><<<2048, B, 0, stream>>>(h2, h, rowptr, srcs, dinv,
                                                conv_b + (size_t)i * UNITS, st, N);
        }
    }

    // ---- ParNet heads (h preserved; scratch h3/hx) ----
    for (int head = 0; head < 2; ++head) {
        const float* wsrc = head == 0 ? phe_w : heu_w;
        const float* bsrc = head == 0 ? phe_b : heu_b;
        const float* wl = head == 0 ? phe_wl : heu_wl;
        const float* bl = head == 0 ? phe_bl : heu_bl;
        float* o = out + (size_t)head * N;

        k_linear_par<<<2048, B, 0, stream>>>(h, h3, wsrc, bsrc, N);
        k_linear_par<<<2048, B, 0, stream>>>(h3, hx, wsrc + (size_t)1 * UNITS * UNITS,
                                             bsrc + (size_t)1 * UNITS, N);
        k_linear_par<<<2048, B, 0, stream>>>(hx, h3, wsrc + (size_t)2 * UNITS * UNITS,
                                             bsrc + (size_t)2 * UNITS, N);
        k_linear_head<<<2048, B, 0, stream>>>(h3, wsrc + (size_t)3 * UNITS * UNITS,
                                              bsrc + (size_t)3 * UNITS, wl, bl, o, N);
    }
}

// Round 10
// 1787.347 us; speedup vs baseline: 2.0542x; 2.0542x over previous
//
#include <hip/hip_runtime.h>
#include <hip/hip_bf16.h>
#include <hip/hip_fp16.h>
#include <math.h>

#define UNITS 64
#define DEPTH_EMB 12
#define DEPTH_PAR 5
#define GN_EPS 1e-5f

// ---------------- CSR build ----------------

__global__ void k_deg(const int* __restrict__ dst, int* __restrict__ cnt, int E) {
    int e = blockIdx.x * blockDim.x + threadIdx.x;
    if (e < E) atomicAdd(&cnt[dst[e]], 1);
}

__global__ void k_dinv(const int* __restrict__ cnt, float* __restrict__ dinv, int n) {
    int i = blockIdx.x * blockDim.x + threadIdx.x;
    if (i < n) dinv[i] = rsqrtf(1.0f + (float)cnt[i]);
}

__global__ void k_chunksum(const int* __restrict__ cnt, int* __restrict__ csum, int n) {
    __shared__ int sd[256];
    int base = blockIdx.x * 1024;
    int s = 0;
    for (int i = threadIdx.x; i < 1024; i += 256) {
        int idx = base + i;
        if (idx < n) s += cnt[idx];
    }
    sd[threadIdx.x] = s;
    __syncthreads();
    for (int off = 128; off > 0; off >>= 1) {
        if (threadIdx.x < off) sd[threadIdx.x] += sd[threadIdx.x + off];
        __syncthreads();
    }
    if (threadIdx.x == 0) csum[blockIdx.x] = sd[0];
}

__global__ void k_scansum(const int* __restrict__ csum, int* __restrict__ coff,
                          int* __restrict__ rowptr, int nchunks) {
    __shared__ int sd[256];
    int tid = threadIdx.x;
    int v = (tid < nchunks) ? csum[tid] : 0;
    sd[tid] = v;
    __syncthreads();
    for (int off = 1; off < 256; off <<= 1) {
        int t = (tid >= off) ? sd[tid - off] : 0;
        __syncthreads();
        sd[tid] += t;
        __syncthreads();
    }
    if (tid < nchunks) coff[tid] = sd[tid] - v;
    if (tid == 0) rowptr[0] = 0;
}

__global__ void k_scanfinal(const int* __restrict__ cnt, const int* __restrict__ coff,
                            int* __restrict__ rowptr, int n) {
    __shared__ int sd[1024];
    int base = blockIdx.x * 1024;
    int tid = threadIdx.x;
    int idx = base + tid;
    int v = (idx < n) ? cnt[idx] : 0;
    sd[tid] = v;
    __syncthreads();
    for (int off = 1; off < 1024; off <<= 1) {
        int t = (tid >= off) ? sd[tid - off] : 0;
        __syncthreads();
        sd[tid] += t;
        __syncthreads();
    }
    if (idx < n) rowptr[idx + 1] = coff[blockIdx.x] + sd[tid];
}

__global__ void k_fill(const int* __restrict__ src, const int* __restrict__ dst,
                       const int* __restrict__ rowptr, int* __restrict__ fill,
                       int* __restrict__ srcs, int E) {
    int e = blockIdx.x * blockDim.x + threadIdx.x;
    if (e >= E) return;
    int s = src[e], d = dst[e];
    int p = rowptr[d] + atomicAdd(&fill[d], 1);
    srcs[p] = s;
}

// ---------------- layer 0: h2 = f16(dinv * (x @ w0)), row-major [N][64] ----------------

__global__ void k_l0(const float* __restrict__ x, const float* __restrict__ w0,
                     const float* __restrict__ dinv, __half* __restrict__ h2, int n) {
    int gid = blockIdx.x * blockDim.x + threadIdx.x;
    if (gid >= n * UNITS) return;
    int node = gid >> 6, c = gid & 63;
    h2[gid] = __float2half(x[node] * w0[c] * dinv[node]);
}

// ---------------- gather: h[d] = dinv[d]*(sum srcs rows + own row) + b ----------------

template <int DO_STATS>
__global__ void k_gather(const __half* __restrict__ h2, float* __restrict__ h,
                         const int* __restrict__ rowptr, const int* __restrict__ srcs,
                         const float* __restrict__ dinv, const float* __restrict__ b,
                         float* __restrict__ stats, int n) {
    int lane = threadIdx.x & 63;
    int wib = threadIdx.x >> 6;
    int wpb = blockDim.x >> 6;
    int gwave = blockIdx.x * wpb + wib;
    int nwaves = gridDim.x * wpb;
    float bj = b[lane];
    float s1 = 0.0f, s2 = 0.0f;

    for (int nd = gwave; nd < n; nd += nwaves) {
        int node = __builtin_amdgcn_readfirstlane(nd);
        int beg = rowptr[node], end = rowptr[node + 1];
        float di = dinv[node];
        float acc0 = __half2float(h2[(size_t)node * UNITS + lane]);   // self row
        float acc1 = 0.0f, acc2 = 0.0f, acc3 = 0.0f;
        int j = beg;
        for (; j + 8 <= end; j += 8) {
            int i0 = srcs[j + 0], i1 = srcs[j + 1], i2 = srcs[j + 2], i3 = srcs[j + 3];
            int i4 = srcs[j + 4], i5 = srcs[j + 5], i6 = srcs[j + 6], i7 = srcs[j + 7];
            float v0 = __half2float(h2[(size_t)i0 * UNITS + lane]);
            float v1 = __half2float(h2[(size_t)i1 * UNITS + lane]);
            float v2 = __half2float(h2[(size_t)i2 * UNITS + lane]);
            float v3 = __half2float(h2[(size_t)i3 * UNITS + lane]);
            float v4 = __half2float(h2[(size_t)i4 * UNITS + lane]);
            float v5 = __half2float(h2[(size_t)i5 * UNITS + lane]);
            float v6 = __half2float(h2[(size_t)i6 * UNITS + lane]);
            float v7 = __half2float(h2[(size_t)i7 * UNITS + lane]);
            acc0 += v0; acc1 += v1; acc2 += v2; acc3 += v3;
            acc0 += v4; acc1 += v5; acc2 += v6; acc3 += v7;
        }
        for (; j + 4 <= end; j += 4) {
            int i0 = srcs[j + 0], i1 = srcs[j + 1], i2 = srcs[j + 2], i3 = srcs[j + 3];
            float v0 = __half2float(h2[(size_t)i0 * UNITS + lane]);
            float v1 = __half2float(h2[(size_t)i1 * UNITS + lane]);
            float v2 = __half2float(h2[(size_t)i2 * UNITS + lane]);
            float v3 = __half2float(h2[(size_t)i3 * UNITS + lane]);
            acc0 += v0; acc1 += v1; acc2 += v2; acc3 += v3;
        }
        for (; j < end; ++j) acc0 += __half2float(h2[(size_t)srcs[j] * UNITS + lane]);
        float acc = (acc0 + acc1) + (acc2 + acc3);
        float hv = fmaf(acc, di, bj);
        h[(size_t)node * UNITS + lane] = hv;
        if (DO_STATS) {
            s1 += hv;
            s2 = fmaf(hv, hv, s2);
        }
    }

    if (DO_STATS) {
        __shared__ float sd[2][4][UNITS];
        sd[0][wib][lane] = s1;
        sd[1][wib][lane] = s2;
        __syncthreads();
        if (threadIdx.x < UNITS) {
            float a1 = 0.0f, a2 = 0.0f;
            for (int r = 0; r < wpb; ++r) {
                a1 += sd[0][r][lane];
                a2 += sd[1][r][lane];
            }
            atomicAdd(&stats[lane], a1);
            atomicAdd(&stats[UNITS + lane], a2);
        }
    }
}

// ---------------- normalize + SiLU (stats finalize fused, float4, grid-stride) ----------------

__global__ void k_norm_silu(float4* __restrict__ h, const float* __restrict__ stats,
                            const float* __restrict__ gamma, const float* __restrict__ beta,
                            const float* __restrict__ alpha, float inv_n, int total4) {
    int tid = blockIdx.x * blockDim.x + threadIdx.x;
    int c = (tid & 15) << 2;
    float A[4], Bc[4];
#pragma unroll
    for (int q = 0; q < 4; ++q) {
        float m = stats[c + q] * inv_n;
        float ex2 = stats[UNITS + c + q] * inv_n;
        float a = alpha[c + q];
        float var = ex2 - m * m * (2.0f * a - a * a);
        float g = gamma[c + q] * rsqrtf(var + GN_EPS);
        A[q] = g;
        Bc[q] = beta[c + q] - g * a * m;
    }
    int stride = gridDim.x * blockDim.x;
    for (int gid = tid; gid < total4; gid += stride) {
        float4 v = h[gid];
        float t0 = fmaf(v.x, A[0], Bc[0]);
        float t1 = fmaf(v.y, A[1], Bc[1]);
        float t2 = fmaf(v.z, A[2], Bc[2]);
        float t3 = fmaf(v.w, A[3], Bc[3]);
        v.x = t0 / (1.0f + __expf(-t0));
        v.y = t1 / (1.0f + __expf(-t1));
        v.z = t2 / (1.0f + __expf(-t2));
        v.w = t3 / (1.0f + __expf(-t3));
        h[gid] = v;
    }
}

// ---------------- embedding linear (2 nodes/iter): h2 = f16(dinv * (in @ W)) ----------------

__global__ void k_linear_emb(const float* __restrict__ in, __half* __restrict__ out,
                             const float* __restrict__ W, const float* __restrict__ dinv,
                             int n, int half) {
    int lane = threadIdx.x & 63;
    int wib = threadIdx.x >> 6;
    int wpb = blockDim.x >> 6;
    int gwave = blockIdx.x * wpb + wib;
    int nwaves = gridDim.x * wpb;

    float w[UNITS];
#pragma unroll
    for (int k = 0; k < UNITS; ++k) w[k] = W[k * UNITS + lane];

    for (int nd = gwave; nd < half; nd += nwaves) {
        int nodeA = __builtin_amdgcn_readfirstlane(nd);
        int nodeBr = nodeA + half;
        bool hasB = nodeBr < n;
        int nodeB = hasB ? nodeBr : nodeA;
        const float* __restrict__ rowA = in + (size_t)nodeA * UNITS;
        const float* __restrict__ rowB = in + (size_t)nodeB * UNITS;
        float diA = dinv[nodeA];
        float diB = dinv[nodeB];
        float aA0 = 0.0f, aA1 = 0.0f, aA2 = 0.0f, aA3 = 0.0f;
        float aB0 = 0.0f, aB1 = 0.0f, aB2 = 0.0f, aB3 = 0.0f;
#pragma unroll
        for (int k = 0; k < UNITS; k += 4) {
            aA0 = fmaf(rowA[k + 0], w[k + 0], aA0);
            aB0 = fmaf(rowB[k + 0], w[k + 0], aB0);
            aA1 = fmaf(rowA[k + 1], w[k + 1], aA1);
            aB1 = fmaf(rowB[k + 1], w[k + 1], aB1);
            aA2 = fmaf(rowA[k + 2], w[k + 2], aA2);
            aB2 = fmaf(rowB[k + 2], w[k + 2], aB2);
            aA3 = fmaf(rowA[k + 3], w[k + 3], aA3);
            aB3 = fmaf(rowB[k + 3], w[k + 3], aB3);
        }
        float accA = (aA0 + aA1) + (aA2 + aA3);
        out[(size_t)nodeA * UNITS + lane] = __float2half(accA * diA);
        if (hasB) {
            float accB = (aB0 + aB1) + (aB2 + aB3);
            out[(size_t)nodeB * UNITS + lane] = __float2half(accB * diB);
        }
    }
}

// ---------------- ParNet linear (2 nodes/iter): out = relu(in + in @ W + b) ----------------

__global__ void k_linear_par(const float* __restrict__ in, float* __restrict__ out,
                             const float* __restrict__ W, const float* __restrict__ b,
                             int n, int half) {
    int lane = threadIdx.x & 63;
    int wib = threadIdx.x >> 6;
    int wpb = blockDim.x >> 6;
    int gwave = blockIdx.x * wpb + wib;
    int nwaves = gridDim.x * wpb;

    float w[UNITS];
#pragma unroll
    for (int k = 0; k < UNITS; ++k) w[k] = W[k * UNITS + lane];
    float bj = b[lane];

    for (int nd = gwave; nd < half; nd += nwaves) {
        int nodeA = __builtin_amdgcn_readfirstlane(nd);
        int nodeBr = nodeA + half;
        bool hasB = nodeBr < n;
        int nodeB = hasB ? nodeBr : nodeA;
        const float* __restrict__ rowA = in + (size_t)nodeA * UNITS;
        const float* __restrict__ rowB = in + (size_t)nodeB * UNITS;
        float aA0 = 0.0f, aA1 = 0.0f, aA2 = 0.0f, aA3 = 0.0f;
        float aB0 = 0.0f, aB1 = 0.0f, aB2 = 0.0f, aB3 = 0.0f;
#pragma unroll
        for (int k = 0; k < UNITS; k += 4) {
            aA0 = fmaf(rowA[k + 0], w[k + 0], aA0);
            aB0 = fmaf(rowB[k + 0], w[k + 0], aB0);
            aA1 = fmaf(rowA[k + 1], w[k + 1], aA1);
            aB1 = fmaf(rowB[k + 1], w[k + 1], aB1);
            aA2 = fmaf(rowA[k + 2], w[k + 2], aA2);
            aB2 = fmaf(rowB[k + 2], w[k + 2], aB2);
            aA3 = fmaf(rowA[k + 3], w[k + 3], aA3);
            aB3 = fmaf(rowB[k + 3], w[k + 3], aB3);
        }
        float accA = (aA0 + aA1) + (aA2 + aA3) + rowA[lane] + bj;
        out[(size_t)nodeA * UNITS + lane] = fmaxf(accA, 0.0f);
        if (hasB) {
            float accB = (aB0 + aB1) + (aB2 + aB3) + rowB[lane] + bj;
            out[(size_t)nodeB * UNITS + lane] = fmaxf(accB, 0.0f);
        }
    }
}

// ---------------- ParNet final linear + head fused (2 nodes/iter) ----------------

__global__ void k_linear_head(const float* __restrict__ in, const float* __restrict__ W,
                              const float* __restrict__ b, const float* __restrict__ wl,
                              const float* __restrict__ bl, float* __restrict__ out,
                              int n, int half) {
    int lane = threadIdx.x & 63;
    int wib = threadIdx.x >> 6;
    int wpb = blockDim.x >> 6;
    int gwave = blockIdx.x * wpb + wib;
    int nwaves = gridDim.x * wpb;

    float w[UNITS];
#pragma unroll
    for (int k = 0; k < UNITS; ++k) w[k] = W[k * UNITS + lane];
    float bj = b[lane];
    float wv = wl[lane];
    float blv = bl[0];

    for (int nd = gwave; nd < half; nd += nwaves) {
        int nodeA = __builtin_amdgcn_readfirstlane(nd);
        int nodeBr = nodeA + half;
        bool hasB = nodeBr < n;
        int nodeB = hasB ? nodeBr : nodeA;
        const float* __restrict__ rowA = in + (size_t)nodeA * UNITS;
        const float* __restrict__ rowB = in + (size_t)nodeB * UNITS;
        float aA0 = 0.0f, aA1 = 0.0f, aA2 = 0.0f, aA3 = 0.0f;
        float aB0 = 0.0f, aB1 = 0.0f, aB2 = 0.0f, aB3 = 0.0f;
#pragma unroll
        for (int k = 0; k < UNITS; k += 4) {
            aA0 = fmaf(rowA[k + 0], w[k + 0], aA0);
            aB0 = fmaf(rowB[k + 0], w[k + 0], aB0);
            aA1 = fmaf(rowA[k + 1], w[k + 1], aA1);
            aB1 = fmaf(rowB[k + 1], w[k + 1], aB1);
            aA2 = fmaf(rowA[k + 2], w[k + 2], aA2);
            aB2 = fmaf(rowB[k + 2], w[k + 2], aB2);
            aA3 = fmaf(rowA[k + 3], w[k + 3], aA3);
            aB3 = fmaf(rowB[k + 3], w[k + 3], aB3);
        }
        float accA = fmaxf((aA0 + aA1) + (aA2 + aA3) + rowA[lane] + bj, 0.0f);
        float accB = fmaxf((aB0 + aB1) + (aB2 + aB3) + rowB[lane] + bj, 0.0f);
        float pA = accA * wv;
        float pB = accB * wv;
#pragma unroll
        for (int off = 32; off > 0; off >>= 1) {
            pA += __shfl_xor(pA, off, 64);
            pB += __shfl_xor(pB, off, 64);
        }
        if (lane == 0) {
            out[nodeA] = 1.0f / (1.0f + __expf(-(pA + blv)));
            if (hasB) out[nodeB] = 1.0f / (1.0f + __expf(-(pB + blv)));
        }
    }
}

// ---------------- host launch ----------------

extern "C" void kernel_launch(void* const* d_in, const int* in_sizes, int n_in,
                              void* d_out, int out_size, void* d_ws, size_t ws_size,
                              hipStream_t stream) {
    const float* x = (const float*)d_in[0];
    const int* ei = (const int*)d_in[1];
    const float* conv_w0 = (const float*)d_in[2];
    const float* conv_w = (const float*)d_in[3];
    const float* conv_b = (const float*)d_in[4];
    const float* gn_gamma = (const float*)d_in[5];
    const float* gn_beta = (const float*)d_in[6];
    const float* gn_alpha = (const float*)d_in[7];
    const float* phe_w = (const float*)d_in[8];
    const float* phe_b = (const float*)d_in[9];
    const float* phe_wl = (const float*)d_in[10];
    const float* phe_bl = (const float*)d_in[11];
    const float* heu_w = (const float*)d_in[12];
    const float* heu_b = (const float*)d_in[13];
    const float* heu_wl = (const float*)d_in[14];
    const float* heu_bl = (const float*)d_in[15];

    const int N = in_sizes[0];
    const int E = in_sizes[1] / 2;
    const int NC = N * UNITS;
    const int NCHUNK1024 = (N + 1023) / 1024;
    const int HALF = (N + 1) / 2;

    const int* src = ei;
    const int* dstp = ei + E;

    char* w = (char*)d_ws;
    float* dinv = (float*)w;  w += (size_t)N * 4;
    float* h = (float*)w;     w += (size_t)NC * 4;
    float* hx = (float*)w;    w += (size_t)NC * 4;   // f16 h2 (embedding) / parnet scratch
    float* h3 = (float*)w;    w += (size_t)NC * 4;   // parnet scratch
    float* stats = (float*)w; w += (size_t)DEPTH_EMB * 128 * 4;
    int* cnt = (int*)w;       w += (size_t)N * 4;
    int* rowptr = (int*)w;    w += (size_t)(N + 1) * 4;
    int* fillc = (int*)w;     w += (size_t)N * 4;
    int* srcs = (int*)w;      w += (size_t)(E + 16) * 4;
    int* csum = (int*)w;      w += 256 * 4;
    int* coff = (int*)w;      w += 256 * 4;

    __half* h2 = (__half*)hx;
    float* out = (float*)d_out;

    const int B = 256;
    const int gE = (E + B - 1) / B;
    const int gN = (N + B - 1) / B;
    const int gNC = (NC + B - 1) / B;

    // ---- CSR build ----
    hipMemsetAsync(cnt, 0, (size_t)N * 4, stream);
    hipMemsetAsync(fillc, 0, (size_t)N * 4, stream);
    hipMemsetAsync(stats, 0, (size_t)DEPTH_EMB * 128 * 4, stream);
    k_deg<<<gE, B, 0, stream>>>(dstp, cnt, E);
    k_dinv<<<gN, B, 0, stream>>>(cnt, dinv, N);
    k_chunksum<<<NCHUNK1024, 256, 0, stream>>>(cnt, csum, N);
    k_scansum<<<1, 256, 0, stream>>>(csum, coff, rowptr, NCHUNK1024);
    k_scanfinal<<<NCHUNK1024, 1024, 0, stream>>>(cnt, coff, rowptr, N);
    k_fill<<<gE, B, 0, stream>>>(src, dstp, rowptr, fillc, srcs, E);

    // ---- GCN embedding ----
    k_l0<<<gNC, B, 0, stream>>>(x, conv_w0, dinv, h2, N);
    for (int i = 0; i < DEPTH_EMB; ++i) {
        float* st = stats + (size_t)i * 128;
        if (i < DEPTH_EMB - 1) {
            k_gather<1><<<2048, B, 0, stream>>>(h2, h, rowptr, srcs, dinv,
                                                conv_b + (size_t)i * UNITS, st, N);
            k_norm_silu<<<2048, B, 0, stream>>>((float4*)h, st,
                                                gn_gamma + (size_t)i * UNITS,
                                                gn_beta + (size_t)i * UNITS,
                                                gn_alpha + (size_t)i * UNITS,
                                                1.0f / (float)N, NC / 4);
            k_linear_emb<<<2048, B, 0, stream>>>(h, h2, conv_w + (size_t)i * UNITS * UNITS,
                                                 dinv, N, HALF);
        } else {
            k_gather<0><<<2048, B, 0, stream>>>(h2, h, rowptr, srcs, dinv,
                                                conv_b + (size_t)i * UNITS, st, N);
        }
    }

    // ---- ParNet heads (h preserved; scratch h3/hx) ----
    for (int head = 0; head < 2; ++head) {
        const float* wsrc = head == 0 ? phe_w : heu_w;
        const float* bsrc = head == 0 ? phe_b : heu_b;
        const float* wl = head == 0 ? phe_wl : heu_wl;
        const float* bl = head == 0 ? phe_bl : heu_bl;
        float* o = out + (size_t)head * N;

        k_linear_par<<<2048, B, 0, stream>>>(h, h3, wsrc, bsrc, N, HALF);
        k_linear_par<<<2048, B, 0, stream>>>(h3, hx, wsrc + (size_t)1 * UNITS * UNITS,
                                             bsrc + (size_t)1 * UNITS, N, HALF);
        k_linear_par<<<2048, B, 0, stream>>>(hx, h3, wsrc + (size_t)2 * UNITS * UNITS,
                                             bsrc + (size_t)2 * UNITS, N, HALF);
        k_linear_head<<<2048, B, 0, stream>>>(h3, wsrc + (size_t)3 * UNITS * UNITS,
                                              bsrc + (size_t)3 * UNITS, wl, bl, o, N, HALF);
    }
}

// Round 11
// 1552.688 us; speedup vs baseline: 2.3646x; 1.1511x over previous
//
#include <hip/hip_runtime.h>
#include <hip/hip_bf16.h>
#include <hip/hip_fp16.h>
#include <math.h>

#define UNITS 64
#define DEPTH_EMB 12
#define DEPTH_PAR 5
#define GN_EPS 1e-5f

// ---------------- CSR build ----------------

__global__ void k_deg(const int* __restrict__ dst, int* __restrict__ cnt, int E) {
    int e = blockIdx.x * blockDim.x + threadIdx.x;
    if (e < E) atomicAdd(&cnt[dst[e]], 1);
}

__global__ void k_dinv(const int* __restrict__ cnt, float* __restrict__ dinv, int n) {
    int i = blockIdx.x * blockDim.x + threadIdx.x;
    if (i < n) dinv[i] = rsqrtf(1.0f + (float)cnt[i]);
}

__global__ void k_chunksum(const int* __restrict__ cnt, int* __restrict__ csum, int n) {
    __shared__ int sd[256];
    int base = blockIdx.x * 1024;
    int s = 0;
    for (int i = threadIdx.x; i < 1024; i += 256) {
        int idx = base + i;
        if (idx < n) s += cnt[idx];
    }
    sd[threadIdx.x] = s;
    __syncthreads();
    for (int off = 128; off > 0; off >>= 1) {
        if (threadIdx.x < off) sd[threadIdx.x] += sd[threadIdx.x + off];
        __syncthreads();
    }
    if (threadIdx.x == 0) csum[blockIdx.x] = sd[0];
}

__global__ void k_scansum(const int* __restrict__ csum, int* __restrict__ coff,
                          int* __restrict__ rowptr, int nchunks) {
    __shared__ int sd[256];
    int tid = threadIdx.x;
    int v = (tid < nchunks) ? csum[tid] : 0;
    sd[tid] = v;
    __syncthreads();
    for (int off = 1; off < 256; off <<= 1) {
        int t = (tid >= off) ? sd[tid - off] : 0;
        __syncthreads();
        sd[tid] += t;
        __syncthreads();
    }
    if (tid < nchunks) coff[tid] = sd[tid] - v;
    if (tid == 0) rowptr[0] = 0;
}

__global__ void k_scanfinal(const int* __restrict__ cnt, const int* __restrict__ coff,
                            int* __restrict__ rowptr, int n) {
    __shared__ int sd[1024];
    int base = blockIdx.x * 1024;
    int tid = threadIdx.x;
    int idx = base + tid;
    int v = (idx < n) ? cnt[idx] : 0;
    sd[tid] = v;
    __syncthreads();
    for (int off = 1; off < 1024; off <<= 1) {
        int t = (tid >= off) ? sd[tid - off] : 0;
        __syncthreads();
        sd[tid] += t;
        __syncthreads();
    }
    if (idx < n) rowptr[idx + 1] = coff[blockIdx.x] + sd[tid];
}

__global__ void k_fill(const int* __restrict__ src, const int* __restrict__ dst,
                       const int* __restrict__ rowptr, int* __restrict__ fill,
                       int* __restrict__ srcs, int E) {
    int e = blockIdx.x * blockDim.x + threadIdx.x;
    if (e >= E) return;
    int s = src[e], d = dst[e];
    int p = rowptr[d] + atomicAdd(&fill[d], 1);
    srcs[p] = s;
}

// ---------------- layer 0: h2 = f16(dinv * (x @ w0)), row-major [N][64] ----------------

__global__ void k_l0(const float* __restrict__ x, const float* __restrict__ w0,
                     const float* __restrict__ dinv, __half* __restrict__ h2, int n) {
    int gid = blockIdx.x * blockDim.x + threadIdx.x;
    if (gid >= n * UNITS) return;
    int node = gid >> 6, c = gid & 63;
    h2[gid] = __float2half(x[node] * w0[c] * dinv[node]);
}

// ---------------- gather: h[d] = dinv[d]*(sum srcs rows + own row) + b ----------------

template <int DO_STATS>
__global__ void k_gather(const __half* __restrict__ h2, float* __restrict__ h,
                         const int* __restrict__ rowptr, const int* __restrict__ srcs,
                         const float* __restrict__ dinv, const float* __restrict__ b,
                         float* __restrict__ stats, int n) {
    int lane = threadIdx.x & 63;
    int wib = threadIdx.x >> 6;
    int wpb = blockDim.x >> 6;
    int gwave = blockIdx.x * wpb + wib;
    int nwaves = gridDim.x * wpb;
    float bj = b[lane];
    float s1 = 0.0f, s2 = 0.0f;

    for (int nd = gwave; nd < n; nd += nwaves) {
        int node = __builtin_amdgcn_readfirstlane(nd);
        int beg = rowptr[node], end = rowptr[node + 1];
        float di = dinv[node];
        float acc0 = __half2float(h2[(size_t)node * UNITS + lane]);   // self row
        float acc1 = 0.0f, acc2 = 0.0f, acc3 = 0.0f;
        int j = beg;
        for (; j + 8 <= end; j += 8) {
            int i0 = srcs[j + 0], i1 = srcs[j + 1], i2 = srcs[j + 2], i3 = srcs[j + 3];
            int i4 = srcs[j + 4], i5 = srcs[j + 5], i6 = srcs[j + 6], i7 = srcs[j + 7];
            float v0 = __half2float(h2[(size_t)i0 * UNITS + lane]);
            float v1 = __half2float(h2[(size_t)i1 * UNITS + lane]);
            float v2 = __half2float(h2[(size_t)i2 * UNITS + lane]);
            float v3 = __half2float(h2[(size_t)i3 * UNITS + lane]);
            float v4 = __half2float(h2[(size_t)i4 * UNITS + lane]);
            float v5 = __half2float(h2[(size_t)i5 * UNITS + lane]);
            float v6 = __half2float(h2[(size_t)i6 * UNITS + lane]);
            float v7 = __half2float(h2[(size_t)i7 * UNITS + lane]);
            acc0 += v0; acc1 += v1; acc2 += v2; acc3 += v3;
            acc0 += v4; acc1 += v5; acc2 += v6; acc3 += v7;
        }
        for (; j + 4 <= end; j += 4) {
            int i0 = srcs[j + 0], i1 = srcs[j + 1], i2 = srcs[j + 2], i3 = srcs[j + 3];
            float v0 = __half2float(h2[(size_t)i0 * UNITS + lane]);
            float v1 = __half2float(h2[(size_t)i1 * UNITS + lane]);
            float v2 = __half2float(h2[(size_t)i2 * UNITS + lane]);
            float v3 = __half2float(h2[(size_t)i3 * UNITS + lane]);
            acc0 += v0; acc1 += v1; acc2 += v2; acc3 += v3;
        }
        for (; j < end; ++j) acc0 += __half2float(h2[(size_t)srcs[j] * UNITS + lane]);
        float acc = (acc0 + acc1) + (acc2 + acc3);
        float hv = fmaf(acc, di, bj);
        h[(size_t)node * UNITS + lane] = hv;
        if (DO_STATS) {
            s1 += hv;
            s2 = fmaf(hv, hv, s2);
        }
    }

    if (DO_STATS) {
        __shared__ float sd[2][4][UNITS];
        sd[0][wib][lane] = s1;
        sd[1][wib][lane] = s2;
        __syncthreads();
        if (threadIdx.x < UNITS) {
            float a1 = 0.0f, a2 = 0.0f;
            for (int r = 0; r < wpb; ++r) {
                a1 += sd[0][r][lane];
                a2 += sd[1][r][lane];
            }
            atomicAdd(&stats[lane], a1);
            atomicAdd(&stats[UNITS + lane], a2);
        }
    }
}

// ---------------- fused GraphNorm + SiLU + linear via intra-wave LDS transpose ----------------
// t = silu(A*h + B) computed LANE-PARALLEL (one exp per element), staged in this wave's
// private LDS slot, then consumed by the k-loop as uniform-address broadcast reads.
// out_h2 = f16( dinv[node] * ( t @ W ) )

__global__ void k_nsl(const float* __restrict__ in, __half* __restrict__ out,
                      const float* __restrict__ W, const float* __restrict__ dinv,
                      const float* __restrict__ stats, const float* __restrict__ gamma,
                      const float* __restrict__ beta, const float* __restrict__ alpha,
                      float inv_n, int n) {
    __shared__ float lds[4][UNITS];     // one 256B slot per wave (4 waves/block)
    int lane = threadIdx.x & 63;
    int wib = threadIdx.x >> 6;
    int wpb = blockDim.x >> 6;
    int gwave = blockIdx.x * wpb + wib;
    int nwaves = gridDim.x * wpb;

    float w[UNITS];
#pragma unroll
    for (int k = 0; k < UNITS; ++k) w[k] = W[k * UNITS + lane];

    // per-lane GraphNorm affine (feature = lane)
    float m = stats[lane] * inv_n;
    float ex2 = stats[UNITS + lane] * inv_n;
    float al = alpha[lane];
    float var = ex2 - m * m * (2.0f * al - al * al);
    float g = gamma[lane] * rsqrtf(var + GN_EPS);
    float A = g;
    float B = beta[lane] - g * al * m;

    for (int nd = gwave; nd < n; nd += nwaves) {
        int node = __builtin_amdgcn_readfirstlane(nd);
        float hv = in[(size_t)node * UNITS + lane];        // coalesced
        float t = fmaf(hv, A, B);
        t = t / (1.0f + __expf(-t));                        // silu, lane-parallel
        lds[wib][lane] = t;                                 // intra-wave dep only
        float di = dinv[node];
        float a0 = 0.0f, a1 = 0.0f, a2 = 0.0f, a3 = 0.0f;
#pragma unroll
        for (int k = 0; k < UNITS; k += 4) {
            float4 tv = *(const float4*)&lds[wib][k];       // uniform-addr broadcast
            a0 = fmaf(tv.x, w[k + 0], a0);
            a1 = fmaf(tv.y, w[k + 1], a1);
            a2 = fmaf(tv.z, w[k + 2], a2);
            a3 = fmaf(tv.w, w[k + 3], a3);
        }
        float acc = (a0 + a1) + (a2 + a3);
        out[(size_t)node * UNITS + lane] = __float2half(acc * di);
    }
}

// ---------------- ParNet linear: out = relu(in + in @ W + b) ----------------

__global__ void k_linear_par(const float* __restrict__ in, float* __restrict__ out,
                             const float* __restrict__ W, const float* __restrict__ b, int n) {
    int lane = threadIdx.x & 63;
    int wib = threadIdx.x >> 6;
    int wpb = blockDim.x >> 6;
    int gwave = blockIdx.x * wpb + wib;
    int nwaves = gridDim.x * wpb;

    float w[UNITS];
#pragma unroll
    for (int k = 0; k < UNITS; ++k) w[k] = W[k * UNITS + lane];
    float bj = b[lane];

    for (int nd = gwave; nd < n; nd += nwaves) {
        int node = __builtin_amdgcn_readfirstlane(nd);
        const float* __restrict__ row = in + (size_t)node * UNITS;
        float a0 = 0.0f, a1 = 0.0f, a2 = 0.0f, a3 = 0.0f;
#pragma unroll
        for (int k = 0; k < UNITS; k += 4) {
            a0 = fmaf(row[k + 0], w[k + 0], a0);
            a1 = fmaf(row[k + 1], w[k + 1], a1);
            a2 = fmaf(row[k + 2], w[k + 2], a2);
            a3 = fmaf(row[k + 3], w[k + 3], a3);
        }
        float acc = (a0 + a1) + (a2 + a3) + row[lane] + bj;
        acc = fmaxf(acc, 0.0f);
        out[(size_t)node * UNITS + lane] = acc;
    }
}

// ---------------- ParNet final linear + head fused ----------------

__global__ void k_linear_head(const float* __restrict__ in, const float* __restrict__ W,
                              const float* __restrict__ b, const float* __restrict__ wl,
                              const float* __restrict__ bl, float* __restrict__ out, int n) {
    int lane = threadIdx.x & 63;
    int wib = threadIdx.x >> 6;
    int wpb = blockDim.x >> 6;
    int gwave = blockIdx.x * wpb + wib;
    int nwaves = gridDim.x * wpb;

    float w[UNITS];
#pragma unroll
    for (int k = 0; k < UNITS; ++k) w[k] = W[k * UNITS + lane];
    float bj = b[lane];
    float wv = wl[lane];
    float blv = bl[0];

    for (int nd = gwave; nd < n; nd += nwaves) {
        int node = __builtin_amdgcn_readfirstlane(nd);
        const float* __restrict__ row = in + (size_t)node * UNITS;
        float a0 = 0.0f, a1 = 0.0f, a2 = 0.0f, a3 = 0.0f;
#pragma unroll
        for (int k = 0; k < UNITS; k += 4) {
            a0 = fmaf(row[k + 0], w[k + 0], a0);
            a1 = fmaf(row[k + 1], w[k + 1], a1);
            a2 = fmaf(row[k + 2], w[k + 2], a2);
            a3 = fmaf(row[k + 3], w[k + 3], a3);
        }
        float acc = (a0 + a1) + (a2 + a3) + row[lane] + bj;
        acc = fmaxf(acc, 0.0f);
        float p = acc * wv;
#pragma unroll
        for (int off = 32; off > 0; off >>= 1) p += __shfl_xor(p, off, 64);
        if (lane == 0) out[node] = 1.0f / (1.0f + __expf(-(p + blv)));
    }
}

// ---------------- host launch ----------------

extern "C" void kernel_launch(void* const* d_in, const int* in_sizes, int n_in,
                              void* d_out, int out_size, void* d_ws, size_t ws_size,
                              hipStream_t stream) {
    const float* x = (const float*)d_in[0];
    const int* ei = (const int*)d_in[1];
    const float* conv_w0 = (const float*)d_in[2];
    const float* conv_w = (const float*)d_in[3];
    const float* conv_b = (const float*)d_in[4];
    const float* gn_gamma = (const float*)d_in[5];
    const float* gn_beta = (const float*)d_in[6];
    const float* gn_alpha = (const float*)d_in[7];
    const float* phe_w = (const float*)d_in[8];
    const float* phe_b = (const float*)d_in[9];
    const float* phe_wl = (const float*)d_in[10];
    const float* phe_bl = (const float*)d_in[11];
    const float* heu_w = (const float*)d_in[12];
    const float* heu_b = (const float*)d_in[13];
    const float* heu_wl = (const float*)d_in[14];
    const float* heu_bl = (const float*)d_in[15];

    const int N = in_sizes[0];
    const int E = in_sizes[1] / 2;
    const int NC = N * UNITS;
    const int NCHUNK1024 = (N + 1023) / 1024;

    const int* src = ei;
    const int* dstp = ei + E;

    char* w = (char*)d_ws;
    float* dinv = (float*)w;  w += (size_t)N * 4;
    float* h = (float*)w;     w += (size_t)NC * 4;
    float* hx = (float*)w;    w += (size_t)NC * 4;   // f16 h2 (embedding) / parnet scratch
    float* h3 = (float*)w;    w += (size_t)NC * 4;   // parnet scratch
    float* stats = (float*)w; w += (size_t)DEPTH_EMB * 128 * 4;
    int* cnt = (int*)w;       w += (size_t)N * 4;
    int* rowptr = (int*)w;    w += (size_t)(N + 1) * 4;
    int* fillc = (int*)w;     w += (size_t)N * 4;
    int* srcs = (int*)w;      w += (size_t)(E + 16) * 4;
    int* csum = (int*)w;      w += 256 * 4;
    int* coff = (int*)w;      w += 256 * 4;

    __half* h2 = (__half*)hx;
    float* out = (float*)d_out;

    const int B = 256;
    const int gE = (E + B - 1) / B;
    const int gN = (N + B - 1) / B;
    const int gNC = (NC + B - 1) / B;

    // ---- CSR build ----
    hipMemsetAsync(cnt, 0, (size_t)N * 4, stream);
    hipMemsetAsync(fillc, 0, (size_t)N * 4, stream);
    hipMemsetAsync(stats, 0, (size_t)DEPTH_EMB * 128 * 4, stream);
    k_deg<<<gE, B, 0, stream>>>(dstp, cnt, E);
    k_dinv<<<gN, B, 0, stream>>>(cnt, dinv, N);
    k_chunksum<<<NCHUNK1024, 256, 0, stream>>>(cnt, csum, N);
    k_scansum<<<1, 256, 0, stream>>>(csum, coff, rowptr, NCHUNK1024);
    k_scanfinal<<<NCHUNK1024, 1024, 0, stream>>>(cnt, coff, rowptr, N);
    k_fill<<<gE, B, 0, stream>>>(src, dstp, rowptr, fillc, srcs, E);

    // ---- GCN embedding ----
    k_l0<<<gNC, B, 0, stream>>>(x, conv_w0, dinv, h2, N);
    for (int i = 0; i < DEPTH_EMB; ++i) {
        float* st = stats + (size_t)i * 128;
        if (i < DEPTH_EMB - 1) {
            k_gather<1><<<2048, B, 0, stream>>>(h2, h, rowptr, srcs, dinv,
                                                conv_b + (size_t)i * UNITS, st, N);
            k_nsl<<<2048, B, 0, stream>>>(h, h2, conv_w + (size_t)i * UNITS * UNITS,
                                          dinv, st,
                                          gn_gamma + (size_t)i * UNITS,
                                          gn_beta + (size_t)i * UNITS,
                                          gn_alpha + (size_t)i * UNITS,
                                          1.0f / (float)N, N);
        } else {
            k_gather<0><<<2048, B, 0, stream>>>(h2, h, rowptr, srcs, dinv,
                                                conv_b + (size_t)i * UNITS, st, N);
        }
    }

    // ---- ParNet heads (h preserved; scratch h3/hx) ----
    for (int head = 0; head < 2; ++head) {
        const float* wsrc = head == 0 ? phe_w : heu_w;
        const float* bsrc = head == 0 ? phe_b : heu_b;
        const float* wl = head == 0 ? phe_wl : heu_wl;
        const float* bl = head == 0 ? phe_bl : heu_bl;
        float* o = out + (size_t)head * N;

        k_linear_par<<<2048, B, 0, stream>>>(h, h3, wsrc, bsrc, N);
        k_linear_par<<<2048, B, 0, stream>>>(h3, hx, wsrc + (size_t)1 * UNITS * UNITS,
                                             bsrc + (size_t)1 * UNITS, N);
        k_linear_par<<<2048, B, 0, stream>>>(hx, h3, wsrc + (size_t)2 * UNITS * UNITS,
                                             bsrc + (size_t)2 * UNITS, N);
        k_linear_head<<<2048, B, 0, stream>>>(h3, wsrc + (size_t)3 * UNITS * UNITS,
                                              bsrc + (size_t)3 * UNITS, wl, bl, o, N);
    }
}